// Round 11
// baseline (481.838 us; speedup 1.0000x reference)
//
#include <hip/hip_runtime.h>
#include <cstdint>
#include <cstddef>

// Problem constants (fixed by the reference setup)
#define N_NODES 50000
#define N_PAD   50048   // 391 * 128 = 782 * 64
#define N_EDGES 800000
#define F_INPUT 128
#define DIM 256
#define NLAYERS 3
#define NGRAPHS 512
#define NMB 782         // 64-row blocks
#define SLS ((size_t)N_PAD * 32)   // slice stride (elements), slice-major activations
#define NREP 16         // BN-stats atomic replicas

typedef __bf16 bf16_t;
typedef bf16_t bf16x8 __attribute__((ext_vector_type(8)));
typedef float f32x4 __attribute__((ext_vector_type(4)));
typedef float v2f __attribute__((ext_vector_type(2)));

__device__ __forceinline__ float bf2f(unsigned short u) {
    union { unsigned u32; float f; } x; x.u32 = ((unsigned)u) << 16; return x.f;
}
__device__ __forceinline__ unsigned short f2bf(float f) {
    union { float f; unsigned u; } x; x.f = f;
    unsigned r = (x.u + 0x7fffu + ((x.u >> 16) & 1u)) >> 16;
    return (unsigned short)r;
}

__device__ __forceinline__ void gl_lds16(const unsigned short* g, unsigned short* l) {
    __builtin_amdgcn_global_load_lds(
        (const __attribute__((address_space(1))) void*)g,
        (__attribute__((address_space(3))) void*)l, 16, 0, 0);
}

// MFMA-fragment-order packing for B (weights): wave fragment load = 64 lanes x 16B
// contiguous (1KB coalesced, L2-resident).
__device__ __forceinline__ size_t frag_off(int n, int k, int K) {
    int nb = n >> 7, half = (n >> 6) & 1, j = (n >> 4) & 3, lm = n & 15;
    int ks = k >> 5, q = (k >> 3) & 3, e = k & 7;
    return ((size_t)(((nb * 2 + half) * 4 + j) * (K >> 5) + ks)) * 512 + (q * 16 + lm) * 8 + e;
}

// ---- merged prep: weight hi/lo frag-packed; x f32->bf16 into SLICE-MAJOR [4][N_PAD][32];
// zero deg + gctr + replicated BN-stats accumulators.
__global__ void k_prep(const float* __restrict__ W_enc, const float* __restrict__ W1,
                       const float* __restrict__ W2, const float* __restrict__ x,
                       unsigned short* __restrict__ wench, unsigned short* __restrict__ wencl,
                       unsigned short* __restrict__ w1h, unsigned short* __restrict__ w1l,
                       unsigned short* __restrict__ w2h, unsigned short* __restrict__ w2l,
                       unsigned short* __restrict__ xb, float* __restrict__ sAB,
                       int* __restrict__ deg, int* __restrict__ gctr) {
    int idx = blockIdx.x * 256 + threadIdx.x;
    if (idx < NLAYERS * NREP * 512) sAB[idx] = 0.f;
    if (idx < N_NODES) deg[idx] = 0;
    if (idx == 0) gctr[0] = 0;
    if (idx < 32768) {                       // W_enc [128][256], K=128
        float w = W_enc[idx];
        int k = idx >> 8, n = idx & 255;
        unsigned short h = f2bf(w), lo = f2bf(w - bf2f(h));
        size_t o = frag_off(n, k, 128);
        wench[o] = h; wencl[o] = lo;
    } else if (idx < 32768 + 196608) {       // W1 [3][256][256], K=256
        int j = idx - 32768;
        int l = j >> 16, r = j & 65535, k = r >> 8, n = r & 255;
        float w = W1[j];
        unsigned short h = f2bf(w), lo = f2bf(w - bf2f(h));
        size_t o = (size_t)l * 65536 + frag_off(n, k, 256);
        w1h[o] = h; w1l[o] = lo;
    } else if (idx < 32768 + 2 * 196608) {   // W2
        int j = idx - 32768 - 196608;
        int l = j >> 16, r = j & 65535, k = r >> 8, n = r & 255;
        float w = W2[j];
        unsigned short h = f2bf(w), lo = f2bf(w - bf2f(h));
        size_t o = (size_t)l * 65536 + frag_off(n, k, 256);
        w2h[o] = h; w2l[o] = lo;
    }
    if (idx < (N_NODES * F_INPUT) / 4) {     // x -> bf16 slice-major, 4 chans at a time
        float4 v = reinterpret_cast<const float4*>(x)[idx];
        ushort4 o;
        o.x = f2bf(v.x); o.y = f2bf(v.y); o.z = f2bf(v.z); o.w = f2bf(v.w);
        int n = idx >> 5, f0 = (idx & 31) * 4;
        *reinterpret_cast<ushort4*>(xb + (size_t)(f0 >> 5) * SLS + (size_t)n * 32 + (f0 & 31)) = o;
    }
}

// ---- degree via global atomics (16/address avg) + graph boundaries
__global__ void k_deg(const int* __restrict__ dst, const int* __restrict__ batch,
                      int* __restrict__ deg, int* __restrict__ gstart) {
    int i = blockIdx.x * 256 + threadIdx.x;
    if (i < N_EDGES) atomicAdd(&deg[dst[i]], 1);
    if (i < N_NODES) {
        int bt = batch[i];
        int pb = (i == 0) ? -1 : batch[i - 1];
        if (bt != pb)
            for (int g = pb + 1; g <= bt; ++g) gstart[g] = i;
        if (i == N_NODES - 1)
            for (int g = bt + 1; g <= NGRAPHS; ++g) gstart[g] = N_NODES;
    }
}

// ---- scan-free compact row allocation: bump-allocate each row's base from one
// global counter (AMDGPU atomic optimizer -> one wave-scan + one atomic per wave).
// Row ORDER in csr16 is arbitrary; k_agg only needs compactness (1.6MB, L2-safe).
__global__ void k_base(const int* __restrict__ deg, int* __restrict__ gctr,
                       int* __restrict__ base, int* __restrict__ cur) {
    int n = blockIdx.x * 256 + threadIdx.x;
    if (n < N_NODES) {
        int d = deg[n];
        int b = atomicAdd(gctr, d);
        base[n] = b;
        cur[n] = b;
    }
}

// ---- CSR fill via atomic cursors (one edge/thread; ~16 atomics/address; compact)
__global__ void k_fill(const int* __restrict__ src, const int* __restrict__ dst,
                       int* __restrict__ cur, unsigned short* __restrict__ csr16) {
    int e = blockIdx.x * 256 + threadIdx.x;
    if (e < N_EDGES) {
        int pos = atomicAdd(&cur[dst[e]], 1);
        csr16[pos] = (unsigned short)src[e];
    }
}

// ---- XCD-sliced plain-sum aggregation (spatial node order).
// slice = blockIdx.x & 7 maps slice->XCD via round-robin dispatch: each XCD's L2
// only gathers from its own 3.2MB slice (L2-resident). DO NOT FUSE (R4: 7x fetch).
// csr16 must stay COMPACT (1.6MB): R10's 6.4MB padded variant thrashed L2
// (FETCH 24->92MB, +8us/dispatch). L2-request-rate bound (~40us floor).
__device__ __forceinline__ void accp(v2f* acc, uint4 v) {
    const unsigned* u = (const unsigned*)&v;
#pragma unroll
    for (int d = 0; d < 4; ++d) {
        union { unsigned q; float f; } lo, hi;
        lo.q = u[d] << 16;            // low bf16 -> f32
        hi.q = u[d] & 0xffff0000u;    // high bf16 -> f32
        acc[d] += (v2f){lo.f, hi.f};
    }
}

__global__ __launch_bounds__(256) void k_agg(const unsigned short* __restrict__ zin,
                                             const int* __restrict__ base,
                                             const int* __restrict__ deg,
                                             const unsigned short* __restrict__ csr16,
                                             unsigned short* __restrict__ z0) {
    int sl = blockIdx.x & 7;
    int wid = threadIdx.x >> 6, lane = threadIdx.x & 63;
    int g = lane >> 2, c = lane & 3;
    int node = (blockIdx.x >> 3) * 64 + wid * 16 + g;   // grid.x = 782*8
    bool valid = node < N_NODES;
    const unsigned short* tc = zin + (size_t)sl * SLS + c * 8;   // per-lane 16B column
    int e = 0, end = 0;
    if (valid) { e = base[node]; end = e + deg[node]; }
    v2f acc[4] = {(v2f){0.f, 0.f}, (v2f){0.f, 0.f}, (v2f){0.f, 0.f}, (v2f){0.f, 0.f}};

    // ---- main: 8 edges per iteration, indices prefetched one stage ahead
    int j[8];
    if (e + 8 <= end) {
#pragma unroll
        for (int i = 0; i < 8; ++i) j[i] = (int)csr16[e + i];
    }
    while (e + 8 <= end) {
        int t0[8];
#pragma unroll
        for (int i = 0; i < 8; ++i) t0[i] = j[i];
        int en = e + 8;
        if (en + 8 <= end) {
#pragma unroll
            for (int i = 0; i < 8; ++i) j[i] = (int)csr16[en + i];
        }
        uint4 v[8];
#pragma unroll
        for (int i = 0; i < 8; ++i) v[i] = *(const uint4*)(tc + (size_t)t0[i] * 32);
#pragma unroll
        for (int i = 0; i < 8; ++i) accp(acc, v[i]);
        e = en;
    }
    // ---- one 4-wide step
    if (e + 4 <= end) {
        int t0[4];
#pragma unroll
        for (int i = 0; i < 4; ++i) t0[i] = (int)csr16[e + i];
        uint4 v[4];
#pragma unroll
        for (int i = 0; i < 4; ++i) v[i] = *(const uint4*)(tc + (size_t)t0[i] * 32);
#pragma unroll
        for (int i = 0; i < 4; ++i) accp(acc, v[i]);
        e += 4;
    }
    // ---- tail singles
    while (e < end) {
        uint4 v0 = *(const uint4*)(tc + (size_t)csr16[e] * 32);
        ++e;
        accp(acc, v0);
    }

    if (valid) {
        uint4 ov = *(const uint4*)(tc + (size_t)node * 32);   // + own h row
        accp(acc, ov);
        uint4 o;
        unsigned short* pw = (unsigned short*)&o;
        const float* af = (const float*)acc;
#pragma unroll
        for (int i = 0; i < 8; ++i) pw[i] = f2bf(af[i]);
        *(uint4*)(z0 + (size_t)sl * SLS + (size_t)node * 32 + c * 8) = o;
    }
}

// ---- encoder GEMM: 64-row blocks. Whole A-tile (16KB) staged ONCE in fragment
// order (1 barrier), then a barrier-free K-loop. LDS = 32KB -> 5 blocks/CU.
__global__ __launch_bounds__(256) void k_enc(const unsigned short* __restrict__ A,
                                             const unsigned short* __restrict__ Whi,
                                             const unsigned short* __restrict__ Wlo,
                                             const float* __restrict__ bias,
                                             unsigned short* __restrict__ C) {
    constexpr int KS = 4;   // K = 128
    __shared__ __align__(16) unsigned short tls[16384];   // A-tile (first 8192) / z staging
    const int tid = threadIdx.x;
    const int m0 = blockIdx.x * 64;
    const int wid = tid >> 6, lane = tid & 63;
    const int lm = lane & 15, q = lane >> 4;
    const unsigned short* fh = Whi + (size_t)wid * 4 * KS * 512 + lane * 8;
    const unsigned short* fl = Wlo + (size_t)wid * 4 * KS * 512 + lane * 8;

    f32x4 acc[4][4];
#pragma unroll
    for (int i = 0; i < 4; ++i)
#pragma unroll
        for (int j = 0; j < 4; ++j) acc[i][j] = (f32x4){0.f, 0.f, 0.f, 0.f};

    // stage whole A-tile: 1024 x 16B chunks, 4 per thread, fragment order
#pragma unroll
    for (int c0 = 0; c0 < 4; ++c0) {
        int cid = c0 * 256 + tid;                 // = ks*256 + i*64 + l
        int ks = cid >> 8, rem = cid & 255;
        int row = (rem >> 6) * 16 + (rem & 15);
        int dq = (rem >> 4) & 3;
        gl_lds16(A + (size_t)ks * SLS + (size_t)(m0 + row) * 32 + dq * 8, &tls[cid * 8]);
    }
    __syncthreads();

#pragma unroll 2
    for (int ks = 0; ks < KS; ++ks) {
        bf16x8 af[4], bh[4], bl[4];
#pragma unroll
        for (int j = 0; j < 4; ++j) {
            bh[j] = *reinterpret_cast<const bf16x8*>(fh + (j * KS + ks) * 512);
            bl[j] = *reinterpret_cast<const bf16x8*>(fl + (j * KS + ks) * 512);
        }
#pragma unroll
        for (int i = 0; i < 4; ++i)
            af[i] = *reinterpret_cast<const bf16x8*>(&tls[(ks * 256 + i * 64 + lane) * 8]);
#pragma unroll
        for (int i = 0; i < 4; ++i)
#pragma unroll
            for (int j = 0; j < 4; ++j) {
                acc[i][j] = __builtin_amdgcn_mfma_f32_16x16x32_bf16(af[i], bl[j], acc[i][j], 0, 0, 0);
                acc[i][j] = __builtin_amdgcn_mfma_f32_16x16x32_bf16(af[i], bh[j], acc[i][j], 0, 0, 0);
            }
    }
    __syncthreads();   // all A reads done before z overwrites tls
    // stage C into LDS slice-major-local [sl][row][ch]
#pragma unroll
    for (int j = 0; j < 4; ++j) {
        int col = wid * 64 + j * 16 + lm;
        float bv = bias[col];
#pragma unroll
        for (int i = 0; i < 4; ++i) {
#pragma unroll
            for (int r = 0; r < 4; ++r)
                tls[(col >> 5) * 2048 + (i * 16 + q * 4 + r) * 32 + (col & 31)] =
                    f2bf(acc[i][j][r] + bv);
        }
    }
    __syncthreads();
#pragma unroll
    for (int c0 = 0; c0 < 8; ++c0) {
        int o = (c0 * 256 + tid) * 8;
        int sl = o >> 11;
        uint4 v = *reinterpret_cast<const uint4*>(&tls[o]);
        *reinterpret_cast<uint4*>(C + (size_t)sl * SLS + (size_t)m0 * 32 + (o - (sl << 11))) = v;
    }
}

// ---- fused MLP (R7-proven shape): BM=64, 512 threads / 8 waves, barrier-free
// K-loops, j-pair wave split (wave = col-group x j-pair, acc[4][2], zero
// redundant B loads). BN stats via replicated atomics (NREP=16).
__global__ __launch_bounds__(512) void k_mlp(const unsigned short* __restrict__ Az,
                                             const unsigned short* __restrict__ W1h,
                                             const unsigned short* __restrict__ W1l,
                                             const float* __restrict__ b1,
                                             const unsigned short* __restrict__ W2h,
                                             const unsigned short* __restrict__ W2l,
                                             const float* __restrict__ b2,
                                             unsigned short* __restrict__ Z,
                                             float* __restrict__ sAB, int M) {
    constexpr int KS = 8;    // K = 256
    __shared__ __align__(16) unsigned short tls[16384];   // A-tile / t / z staging, 32KB
    const int tid = threadIdx.x;
    const int m0 = blockIdx.x * 64;
    const int wave = tid >> 6, lane = tid & 63;
    const int wid = wave >> 1;     // 64-col group 0..3
    const int jp  = wave & 1;      // j-pair 0..1 (j = jp*2 + j2)
    const int lm = lane & 15, q = lane >> 4;
    float* sABr = sAB + (blockIdx.x & (NREP - 1)) * 512;
    const unsigned short* f1h = W1h + (size_t)wid * 4 * KS * 512 + lane * 8;
    const unsigned short* f1l = W1l + (size_t)wid * 4 * KS * 512 + lane * 8;
    const unsigned short* f2h = W2h + (size_t)wid * 4 * KS * 512 + lane * 8;
    const unsigned short* f2l = W2l + (size_t)wid * 4 * KS * 512 + lane * 8;

    f32x4 acc[4][2];
#pragma unroll
    for (int i = 0; i < 4; ++i)
#pragma unroll
        for (int j = 0; j < 2; ++j) acc[i][j] = (f32x4){0.f, 0.f, 0.f, 0.f};

    // stage whole A-tile: 2048 x 16B chunks, 4 per thread, fragment order
#pragma unroll
    for (int c0 = 0; c0 < 4; ++c0) {
        int cid = c0 * 512 + tid;                 // = ks*256 + i*64 + l
        int ks = cid >> 8, rem = cid & 255;
        int row = (rem >> 6) * 16 + (rem & 15);
        int dq = (rem >> 4) & 3;
        gl_lds16(Az + (size_t)ks * SLS + (size_t)(m0 + row) * 32 + dq * 8, &tls[cid * 8]);
    }
    __syncthreads();

    // GEMM-1: barrier-free, B loads pipeline across iterations
#pragma unroll 2
    for (int ks = 0; ks < KS; ++ks) {
        bf16x8 af[4], bh[2], bl[2];
#pragma unroll
        for (int j2 = 0; j2 < 2; ++j2) {
            int j = jp * 2 + j2;
            bh[j2] = *reinterpret_cast<const bf16x8*>(f1h + (j * KS + ks) * 512);
            bl[j2] = *reinterpret_cast<const bf16x8*>(f1l + (j * KS + ks) * 512);
        }
#pragma unroll
        for (int i = 0; i < 4; ++i)
            af[i] = *reinterpret_cast<const bf16x8*>(&tls[(ks * 256 + i * 64 + lane) * 8]);
#pragma unroll
        for (int i = 0; i < 4; ++i)
#pragma unroll
            for (int j2 = 0; j2 < 2; ++j2) {
                acc[i][j2] = __builtin_amdgcn_mfma_f32_16x16x32_bf16(af[i], bl[j2], acc[i][j2], 0, 0, 0);
                acc[i][j2] = __builtin_amdgcn_mfma_f32_16x16x32_bf16(af[i], bh[j2], acc[i][j2], 0, 0, 0);
            }
    }
    __syncthreads();   // all A reads done before t overwrites tls
    // epilogue-1: t = relu(acc + b1) -> tls in FRAGMENT order
#pragma unroll
    for (int j2 = 0; j2 < 2; ++j2) {
        int col = wid * 64 + (jp * 2 + j2) * 16 + lm;
        float bv = b1[col];
        int ks2 = col >> 5;
        int q2 = (col >> 3) & 3;
        int e2 = col & 7;
#pragma unroll
        for (int i = 0; i < 4; ++i) {
#pragma unroll
            for (int r = 0; r < 4; ++r)
                tls[((i * 8 + ks2) * 64 + q2 * 16 + q * 4 + r) * 8 + e2] =
                    f2bf(fmaxf(acc[i][j2][r] + bv, 0.f));
        }
    }
    __syncthreads();

    // GEMM-2: A-fragments straight from tls (conflict-free), fragment B
#pragma unroll
    for (int i = 0; i < 4; ++i)
#pragma unroll
        for (int j = 0; j < 2; ++j) acc[i][j] = (f32x4){0.f, 0.f, 0.f, 0.f};
#pragma unroll 2
    for (int ks = 0; ks < KS; ++ks) {
        bf16x8 af[4], bh[2], bl[2];
#pragma unroll
        for (int j2 = 0; j2 < 2; ++j2) {
            int j = jp * 2 + j2;
            bh[j2] = *reinterpret_cast<const bf16x8*>(f2h + (j * KS + ks) * 512);
            bl[j2] = *reinterpret_cast<const bf16x8*>(f2l + (j * KS + ks) * 512);
        }
#pragma unroll
        for (int i = 0; i < 4; ++i)
            af[i] = *reinterpret_cast<const bf16x8*>(&tls[((i * 8 + ks) * 64 + lane) * 8]);
#pragma unroll
        for (int i = 0; i < 4; ++i)
#pragma unroll
            for (int j2 = 0; j2 < 2; ++j2) {
                acc[i][j2] = __builtin_amdgcn_mfma_f32_16x16x32_bf16(af[i], bl[j2], acc[i][j2], 0, 0, 0);
                acc[i][j2] = __builtin_amdgcn_mfma_f32_16x16x32_bf16(af[i], bh[j2], acc[i][j2], 0, 0, 0);
            }
    }
    __syncthreads();   // all tls reads done before overwrite with z

    // epilogue-2: stats (shfl-reduced, one replicated atomicAdd pair per col) + z -> tls
#pragma unroll
    for (int j2 = 0; j2 < 2; ++j2) {
        int col = wid * 64 + (jp * 2 + j2) * 16 + lm;
        float bv = b2[col];
        float s = 0.f, s2 = 0.f;
#pragma unroll
        for (int i = 0; i < 4; ++i) {
#pragma unroll
            for (int r = 0; r < 4; ++r) {
                int row = i * 16 + q * 4 + r;
                float v = acc[i][j2][r] + bv;
                if (m0 + row < M) { s += v; s2 = fmaf(v, v, s2); }
                tls[(col >> 5) * 2048 + row * 32 + (col & 31)] = f2bf(v);
            }
        }
        s += __shfl_xor(s, 16); s += __shfl_xor(s, 32);
        s2 += __shfl_xor(s2, 16); s2 += __shfl_xor(s2, 32);
        if (q == 0) {
            atomicAdd(&sABr[col], s);
            atomicAdd(&sABr[256 + col], s2);
        }
    }
    __syncthreads();
#pragma unroll
    for (int c0 = 0; c0 < 4; ++c0) {
        int o = (c0 * 512 + tid) * 8;
        int sl = o >> 11;
        uint4 v = *reinterpret_cast<const uint4*>(&tls[o]);
        *reinterpret_cast<uint4*>(Z + (size_t)sl * SLS + (size_t)m0 * 32 + (o - (sl << 11))) = v;
    }
}

// ---- vectorized graph mean-pool of relu(A*z+B); writes h back IN PLACE.
// BN affine (A,B) from the NREP replicated atomic stats (summed in prologue,
// L2-broadcast). 8 groups of 32 lanes; group = slice; lane = (rsub, cc).
__global__ void k_pool(unsigned short* __restrict__ z, const float* __restrict__ sAB,
                       const float* __restrict__ gamma, const float* __restrict__ beta,
                       const int* __restrict__ gstart, float* __restrict__ partl) {
    __shared__ float Asm[256], Bsm[256];
    int g = blockIdx.x, sp = blockIdx.y, tid = threadIdx.x;
    {
        float s = 0.f, s2 = 0.f;
#pragma unroll
        for (int r = 0; r < NREP; ++r) {
            s += sAB[r * 512 + tid];
            s2 += sAB[r * 512 + 256 + tid];
        }
        float mean = s * (1.f / N_NODES);
        float var = s2 * (1.f / N_NODES) - mean * mean;
        float inv = rsqrtf(var + 1e-5f);
        float A = gamma[tid] * inv;
        Asm[tid] = A;
        Bsm[tid] = beta[tid] - mean * A;
    }
    __syncthreads();
    int grp = tid >> 5, l = tid & 31;
    int rsub = l >> 2, cc = l & 3;
    float A[8], B[8];
#pragma unroll
    for (int i = 0; i < 8; ++i) {
        A[i] = Asm[grp * 32 + cc * 8 + i];
        B[i] = Bsm[grp * 32 + cc * 8 + i];
    }
    int beg = gstart[g], c = gstart[g + 1] - beg;
    int chunk = (c + 3) >> 2;
    int r0 = beg + sp * chunk;
    int r1 = beg + c;
    int rlim = r0 + chunk;
    if (rlim < r1) r1 = rlim;
    unsigned short* zp = z + (size_t)grp * SLS + cc * 8;
    float acc[8] = {0.f, 0.f, 0.f, 0.f, 0.f, 0.f, 0.f, 0.f};
    for (int r = r0 + rsub; r < r1; r += 8) {
        uint4 v = *reinterpret_cast<const uint4*>(zp + (size_t)r * 32);
        const unsigned short* pv = (const unsigned short*)&v;
        uint4 o;
        unsigned short* pw = (unsigned short*)&o;
#pragma unroll
        for (int i = 0; i < 8; ++i) {
            float x = fmaxf(fmaf(A[i], bf2f(pv[i]), B[i]), 0.f);
            pw[i] = f2bf(x);
            acc[i] += x;
        }
        *reinterpret_cast<uint4*>(zp + (size_t)r * 32) = o;
    }
#pragma unroll
    for (int m = 4; m <= 16; m <<= 1)
#pragma unroll
        for (int i = 0; i < 8; ++i) acc[i] += __shfl_xor(acc[i], m, 64);
    if (rsub == 0) {
        float* pp = partl + (size_t)(g * 4 + sp) * 256 + grp * 32 + cc * 8;
#pragma unroll
        for (int i = 0; i < 8; ++i) pp[i] = acc[i];
    }
}

// ---- FC head: sums pool partials, divides by cnt, 2-layer MLP
__global__ __launch_bounds__(1024) void k_fc(const float* __restrict__ part,
                                             const int* __restrict__ gstart,
                                             const float* __restrict__ W1,
                                             const float* __restrict__ b1,
                                             const float* __restrict__ W2,
                                             const float* __restrict__ b2,
                                             float* __restrict__ out) {
    __shared__ float gs[DIM * NLAYERS];
    __shared__ float pt[8][128];
    __shared__ float red2[2];
    int g = blockIdx.x, t = threadIdx.x;
    float invc = 1.f / fmaxf((float)(gstart[g + 1] - gstart[g]), 1.f);
    for (int i = t; i < DIM * NLAYERS; i += 1024) {
        int l = i >> 8, c = i & 255;
        const float* pl = part + ((size_t)(l * NGRAPHS + g) * 4) * 256 + c;
        gs[i] = (pl[0] + pl[256] + pl[512] + pl[768]) * invc;
    }
    __syncthreads();
    int o = t & 127, kk = t >> 7;
    float acc = 0.f;
    const float* wp = W1 + (size_t)(kk * 96) * 128 + o;
#pragma unroll 4
    for (int k = 0; k < 96; ++k) acc = fmaf(gs[kk * 96 + k], wp[(size_t)k * 128], acc);
    pt[kk][o] = acc;
    __syncthreads();
    if (t < 128) {
        float v = b1[o];
#pragma unroll
        for (int p = 0; p < 8; ++p) v += pt[p][o];
        v = fmaxf(v, 0.f) * W2[o];
#pragma unroll
        for (int off = 32; off; off >>= 1) v += __shfl_down(v, off, 64);
        if ((t & 63) == 0) red2[t >> 6] = v;
    }
    __syncthreads();
    if (t == 0) out[g] = red2[0] + red2[1] + b2[0];
}

extern "C" void kernel_launch(void* const* d_in, const int* in_sizes, int n_in,
                              void* d_out, int out_size, void* d_ws, size_t ws_size,
                              hipStream_t stream) {
    const float* x = (const float*)d_in[0];
    const int* ei = (const int*)d_in[1];
    const int* batch = (const int*)d_in[2];
    const float* W_enc = (const float*)d_in[4];
    const float* b_enc = (const float*)d_in[5];
    const float* W1 = (const float*)d_in[6];
    const float* b1 = (const float*)d_in[7];
    const float* W2 = (const float*)d_in[8];
    const float* b2 = (const float*)d_in[9];
    const float* gamma = (const float*)d_in[10];
    const float* beta = (const float*)d_in[11];
    const float* Wfc1 = (const float*)d_in[12];
    const float* bfc1 = (const float*)d_in[13];
    const float* Wfc2 = (const float*)d_in[14];
    const float* bfc2 = (const float*)d_in[15];
    float* out = (float*)d_out;
    const int* srcp = ei;
    const int* dstp = ei + N_EDGES;

    // Workspace bump allocator (~70 MB)
    char* w = (char*)d_ws;
    auto alloc = [&](size_t b) -> char* {
        char* p = w;
        w += (b + 255) & ~(size_t)255;
        return p;
    };
    unsigned short* xb   = (unsigned short*)alloc((size_t)N_PAD * F_INPUT * 2);  // [4][N_PAD][32]
    unsigned short* hbuf = (unsigned short*)alloc(8 * SLS * 2);  // enc out / z / h (in-place)
    unsigned short* zA   = (unsigned short*)alloc(8 * SLS * 2);  // agg out
    unsigned short* wench = (unsigned short*)alloc(F_INPUT * DIM * 2);
    unsigned short* wencl = (unsigned short*)alloc(F_INPUT * DIM * 2);
    unsigned short* w1h = (unsigned short*)alloc((size_t)NLAYERS * DIM * DIM * 2);
    unsigned short* w1l = (unsigned short*)alloc((size_t)NLAYERS * DIM * DIM * 2);
    unsigned short* w2h = (unsigned short*)alloc((size_t)NLAYERS * DIM * DIM * 2);
    unsigned short* w2l = (unsigned short*)alloc((size_t)NLAYERS * DIM * DIM * 2);
    unsigned short* csr16 = (unsigned short*)alloc((size_t)N_EDGES * 2);  // compact CSR
    int* deg = (int*)alloc((size_t)N_NODES * 4);
    int* base = (int*)alloc((size_t)N_NODES * 4);
    int* cur = (int*)alloc((size_t)N_NODES * 4);
    int* gctr = (int*)alloc(256);
    int* gstart = (int*)alloc((NGRAPHS + 1) * 4);
    float* sAB = (float*)alloc((size_t)NLAYERS * NREP * 512 * 4);  // replicated BN accumulators
    float* part = (float*)alloc((size_t)NLAYERS * NGRAPHS * 4 * 256 * 4);

    // prep: weights hi/lo fragment-packed + x->bf16 slice-major + zeroing
    k_prep<<<6250, 256, 0, stream>>>(W_enc, W1, W2, x, wench, wencl, w1h, w1l, w2h, w2l,
                                     xb, sAB, deg, gctr);

    // compact CSR build, scan-free (bump-allocated row bases, arbitrary row order)
    const int NB = (N_NODES + 255) / 256;   // 196
    const int NEB = (N_EDGES + 255) / 256;  // 3125
    k_deg<<<NEB, 256, 0, stream>>>(dstp, batch, deg, gstart);
    k_base<<<NB, 256, 0, stream>>>(deg, gctr, base, cur);
    k_fill<<<NEB, 256, 0, stream>>>(srcp, dstp, cur, csr16);

    // encoder: h = x @ W_enc + b_enc -> hbuf (slice-major)
    k_enc<<<NMB, 256, 0, stream>>>(xb, wench, wencl, b_enc, hbuf);

    dim3 pgrid(NGRAPHS, 4);
    const int AGRID = 782 * 8;
    for (int l = 0; l < NLAYERS; ++l) {
        k_agg<<<AGRID, 256, 0, stream>>>(hbuf, base, deg, csr16, zA);
        k_mlp<<<NMB, 512, 0, stream>>>(zA, w1h + l * 65536, w1l + l * 65536, b1 + l * DIM,
                                       w2h + l * 65536, w2l + l * 65536, b2 + l * DIM,
                                       hbuf, sAB + l * NREP * 512, N_NODES);
        k_pool<<<pgrid, 256, 0, stream>>>(hbuf, sAB + l * NREP * 512, gamma + l * DIM,
                                          beta + l * DIM, gstart,
                                          part + (size_t)l * NGRAPHS * 4 * 256);
    }
    k_fc<<<NGRAPHS, 1024, 0, stream>>>(part, gstart, Wfc1, bfc1, Wfc2, bfc2, out);
}

// Round 12
// 457.716 us; speedup vs baseline: 1.0527x; 1.0527x over previous
//
#include <hip/hip_runtime.h>
#include <cstdint>
#include <cstddef>

// Problem constants (fixed by the reference setup)
#define N_NODES 50000
#define N_PAD   50048   // 391 * 128 = 782 * 64
#define N_EDGES 800000
#define F_INPUT 128
#define DIM 256
#define NLAYERS 3
#define NGRAPHS 512
#define NBH 64          // histogram/fill blocks
#define EPB 12500       // edges per histogram block
#define NMB 782         // 64-row blocks (N_PAD/64)
#define SLS ((size_t)N_PAD * 32)   // slice stride (elements), slice-major activations
#define NREP 8          // BN-stats atomic replicas (contention / 8)

typedef __bf16 bf16_t;
typedef bf16_t bf16x8 __attribute__((ext_vector_type(8)));
typedef float f32x4 __attribute__((ext_vector_type(4)));
typedef float v2f __attribute__((ext_vector_type(2)));

__device__ __forceinline__ float bf2f(unsigned short u) {
    union { unsigned u32; float f; } x; x.u32 = ((unsigned)u) << 16; return x.f;
}
__device__ __forceinline__ unsigned short f2bf(float f) {
    union { float f; unsigned u; } x; x.f = f;
    unsigned r = (x.u + 0x7fffu + ((x.u >> 16) & 1u)) >> 16;
    return (unsigned short)r;
}

__device__ __forceinline__ void gl_lds16(const unsigned short* g, unsigned short* l) {
    __builtin_amdgcn_global_load_lds(
        (const __attribute__((address_space(1))) void*)g,
        (__attribute__((address_space(3))) void*)l, 16, 0, 0);
}

// MFMA-fragment-order packing for B (weights): wave fragment load = 64 lanes x 16B
// contiguous (1KB coalesced, L2-resident).
__device__ __forceinline__ size_t frag_off(int n, int k, int K) {
    int nb = n >> 7, half = (n >> 6) & 1, j = (n >> 4) & 3, lm = n & 15;
    int ks = k >> 5, q = (k >> 3) & 3, e = k & 7;
    return ((size_t)(((nb * 2 + half) * 4 + j) * (K >> 5) + ks)) * 512 + (q * 16 + lm) * 8 + e;
}

// ---- merged prep: weight hi/lo frag-packed; x f32->bf16 into SLICE-MAJOR [4][N_PAD][32];
// zero the replicated BN-stats atomic accumulators (3 layers x NREP x 512).
__global__ void k_prep(const float* __restrict__ W_enc, const float* __restrict__ W1,
                       const float* __restrict__ W2, const float* __restrict__ x,
                       unsigned short* __restrict__ wench, unsigned short* __restrict__ wencl,
                       unsigned short* __restrict__ w1h, unsigned short* __restrict__ w1l,
                       unsigned short* __restrict__ w2h, unsigned short* __restrict__ w2l,
                       unsigned short* __restrict__ xb, float* __restrict__ sAB) {
    int idx = blockIdx.x * 256 + threadIdx.x;
    if (idx < NLAYERS * NREP * 512) sAB[idx] = 0.f;
    if (idx < 32768) {                       // W_enc [128][256], K=128
        float w = W_enc[idx];
        int k = idx >> 8, n = idx & 255;
        unsigned short h = f2bf(w), lo = f2bf(w - bf2f(h));
        size_t o = frag_off(n, k, 128);
        wench[o] = h; wencl[o] = lo;
    } else if (idx < 32768 + 196608) {       // W1 [3][256][256], K=256
        int j = idx - 32768;
        int l = j >> 16, r = j & 65535, k = r >> 8, n = r & 255;
        float w = W1[j];
        unsigned short h = f2bf(w), lo = f2bf(w - bf2f(h));
        size_t o = (size_t)l * 65536 + frag_off(n, k, 256);
        w1h[o] = h; w1l[o] = lo;
    } else if (idx < 32768 + 2 * 196608) {   // W2
        int j = idx - 32768 - 196608;
        int l = j >> 16, r = j & 65535, k = r >> 8, n = r & 255;
        float w = W2[j];
        unsigned short h = f2bf(w), lo = f2bf(w - bf2f(h));
        size_t o = (size_t)l * 65536 + frag_off(n, k, 256);
        w2h[o] = h; w2l[o] = lo;
    }
    if (idx < (N_NODES * F_INPUT) / 4) {     // x -> bf16 slice-major, 4 chans at a time
        float4 v = reinterpret_cast<const float4*>(x)[idx];
        ushort4 o;
        o.x = f2bf(v.x); o.y = f2bf(v.y); o.z = f2bf(v.z); o.w = f2bf(v.w);
        int n = idx >> 5, f0 = (idx & 31) * 4;
        *reinterpret_cast<ushort4*>(xb + (size_t)(f0 >> 5) * SLS + (size_t)n * 32 + (f0 & 31)) = o;
    }
}

// ---- per-block LDS histogram of dst (packed 2x16-bit, 2 node-range passes)
__global__ __launch_bounds__(512) void k_count(const int* __restrict__ dst,
                                               unsigned* __restrict__ slab) {
    __shared__ unsigned bins[16384];
    int b = blockIdx.x, t = threadIdx.x;
    int e0 = b * EPB, e1 = e0 + EPB;
    for (int pass = 0; pass < 2; ++pass) {
        int lo = pass << 15;
        int words = pass ? 8616 : 16384;
        for (int w = t; w < 16384; w += 512) bins[w] = 0;
        __syncthreads();
        for (int e = e0 + t; e < e1; e += 512) {
            int r = dst[e] - lo;
            if ((unsigned)r < 32768u)
                atomicAdd(&bins[r >> 1], 1u << ((r & 1) * 16));
        }
        __syncthreads();
        unsigned* out = slab + b * 25000 + (pass ? 16384 : 0);
        for (int w = t; w < words; w += 512) out[w] = bins[w];
        __syncthreads();
    }
}

// ---- reduce count slabs -> deg; graph boundaries from sorted batch -> gstart
__global__ void k_degred(const unsigned* __restrict__ slab, const int* __restrict__ batch,
                         int* __restrict__ deg, int* __restrict__ gstart) {
    int i = blockIdx.x * 256 + threadIdx.x;
    if (i < 25000) {
        unsigned s = 0;
#pragma unroll 8
        for (int b = 0; b < NBH; ++b) s += slab[b * 25000 + i];
        deg[2 * i] = s & 0xffff;
        deg[2 * i + 1] = s >> 16;
    }
    if (i < N_NODES) {
        int bt = batch[i];
        int pb = (i == 0) ? -1 : batch[i - 1];
        if (bt != pb)
            for (int g = pb + 1; g <= bt; ++g) gstart[g] = i;
        if (i == N_NODES - 1)
            for (int g = bt + 1; g <= NGRAPHS; ++g) gstart[g] = N_NODES;
    }
}

// ---- scan step 1: per-block inclusive scan of deg
__global__ void k_scan1(const int* __restrict__ deg, int* __restrict__ rp1,
                        int* __restrict__ bsum) {
    __shared__ int s[256];
    int t = threadIdx.x, b = blockIdx.x, i = b * 256 + t;
    int v = (i < N_NODES) ? deg[i] : 0;
    s[t] = v; __syncthreads();
    for (int off = 1; off < 256; off <<= 1) {
        int x = (t >= off) ? s[t - off] : 0;
        __syncthreads(); s[t] += x; __syncthreads();
    }
    if (i < N_NODES) rp1[i] = s[t];
    if (t == 255) bsum[b] = s[255];
}

// ---- scan step 2: exclusive scan of block sums
__global__ void k_scan2(const int* __restrict__ bsum, int* __restrict__ boff, int nb) {
    __shared__ int s[256];
    int t = threadIdx.x;
    int v = (t < nb) ? bsum[t] : 0;
    s[t] = v; __syncthreads();
    for (int off = 1; off < 256; off <<= 1) {
        int x = (t >= off) ? s[t - off] : 0;
        __syncthreads(); s[t] += x; __syncthreads();
    }
    if (t < nb) boff[t] = s[t] - v;
}

// ---- scan step 3: add block offsets; finalize row_ptr[0]
__global__ void k_scan3(int* __restrict__ row_ptr, const int* __restrict__ boff) {
    int t = threadIdx.x, b = blockIdx.x, i = b * 256 + t;
    if (i < N_NODES) row_ptr[1 + i] += boff[b];
    if (i == 0) row_ptr[0] = 0;
}

// ---- per-(block,node) exclusive bases from count slabs
__global__ void k_base(const unsigned* __restrict__ slab, const int* __restrict__ row_ptr,
                       int* __restrict__ base) {
    int n = blockIdx.x * 256 + threadIdx.x;
    if (n >= N_NODES) return;
    int w = n >> 1, sh = (n & 1) * 16;
    int cur = row_ptr[n];
#pragma unroll 4
    for (int b = 0; b < NBH; ++b) {
        base[b * N_NODES + n] = cur;
        cur += (slab[b * 25000 + w] >> sh) & 0xffff;
    }
}

// ---- CSR fill with LDS cursors (no global atomics), u16 indices.
// Produces sequential write-combined stores + spatially-ordered rows (k_agg
// FETCH minimum 24.4MB). R8-R11 alternatives (global-atomic / scan-free /
// padded) all regressed; this is the proven-fastest build.
__global__ __launch_bounds__(512) void k_fill2(const int* __restrict__ src,
                                               const int* __restrict__ dst,
                                               const int* __restrict__ base,
                                               unsigned short* __restrict__ csr16) {
    __shared__ unsigned bins[16384];
    int b = blockIdx.x, t = threadIdx.x;
    int e0 = b * EPB, e1 = e0 + EPB;
    for (int pass = 0; pass < 2; ++pass) {
        int lo = pass << 15;
        for (int w = t; w < 16384; w += 512) bins[w] = 0;
        __syncthreads();
        for (int e = e0 + t; e < e1; e += 512) {
            int d = dst[e];
            int r = d - lo;
            if ((unsigned)r < 32768u) {
                int sh = (r & 1) * 16;
                unsigned old = atomicAdd(&bins[r >> 1], 1u << sh);
                int local = (old >> sh) & 0xffff;
                csr16[base[b * N_NODES + d] + local] = (unsigned short)src[e];
            }
        }
        __syncthreads();
    }
}

// ---- XCD-sliced plain-sum aggregation (spatial node order).
// slice = blockIdx.x & 7 maps slice->XCD via round-robin dispatch: each XCD's L2
// only gathers from its own 3.2MB slice (L2-resident). DO NOT FUSE (R4: 7x fetch).
// L2-request-rate bound (~40us floor, R5/R7); 8-wide unroll + pk-add accumulators.
__device__ __forceinline__ void accp(v2f* acc, uint4 v) {
    const unsigned* u = (const unsigned*)&v;
#pragma unroll
    for (int d = 0; d < 4; ++d) {
        union { unsigned q; float f; } lo, hi;
        lo.q = u[d] << 16;            // low bf16 -> f32
        hi.q = u[d] & 0xffff0000u;    // high bf16 -> f32
        acc[d] += (v2f){lo.f, hi.f};
    }
}

__global__ __launch_bounds__(256) void k_agg(const unsigned short* __restrict__ zin,
                                             const int* __restrict__ row_ptr,
                                             const unsigned short* __restrict__ csr16,
                                             unsigned short* __restrict__ z0) {
    int sl = blockIdx.x & 7;
    int wid = threadIdx.x >> 6, lane = threadIdx.x & 63;
    int g = lane >> 2, c = lane & 3;
    int node = (blockIdx.x >> 3) * 64 + wid * 16 + g;   // grid.x = 782*8
    bool valid = node < N_NODES;
    const unsigned short* tc = zin + (size_t)sl * SLS + c * 8;   // per-lane 16B column
    int e = 0, end = 0;
    if (valid) { e = row_ptr[node]; end = row_ptr[node + 1]; }
    v2f acc[4] = {(v2f){0.f, 0.f}, (v2f){0.f, 0.f}, (v2f){0.f, 0.f}, (v2f){0.f, 0.f}};

    // ---- main: 8 edges per iteration, indices prefetched one stage ahead
    int j[8];
    if (e + 8 <= end) {
#pragma unroll
        for (int i = 0; i < 8; ++i) j[i] = (int)csr16[e + i];
    }
    while (e + 8 <= end) {
        int t0[8];
#pragma unroll
        for (int i = 0; i < 8; ++i) t0[i] = j[i];
        int en = e + 8;
        if (en + 8 <= end) {
#pragma unroll
            for (int i = 0; i < 8; ++i) j[i] = (int)csr16[en + i];
        }
        uint4 v[8];
#pragma unroll
        for (int i = 0; i < 8; ++i) v[i] = *(const uint4*)(tc + (size_t)t0[i] * 32);
#pragma unroll
        for (int i = 0; i < 8; ++i) accp(acc, v[i]);
        e = en;
    }
    // ---- one 4-wide step
    if (e + 4 <= end) {
        int t0[4];
#pragma unroll
        for (int i = 0; i < 4; ++i) t0[i] = (int)csr16[e + i];
        uint4 v[4];
#pragma unroll
        for (int i = 0; i < 4; ++i) v[i] = *(const uint4*)(tc + (size_t)t0[i] * 32);
#pragma unroll
        for (int i = 0; i < 4; ++i) accp(acc, v[i]);
        e += 4;
    }
    // ---- tail singles
    while (e < end) {
        uint4 v0 = *(const uint4*)(tc + (size_t)csr16[e] * 32);
        ++e;
        accp(acc, v0);
    }

    if (valid) {
        uint4 ov = *(const uint4*)(tc + (size_t)node * 32);   // + own h row
        accp(acc, ov);
        uint4 o;
        unsigned short* pw = (unsigned short*)&o;
        const float* af = (const float*)acc;
#pragma unroll
        for (int i = 0; i < 8; ++i) pw[i] = f2bf(af[i]);
        *(uint4*)(z0 + (size_t)sl * SLS + (size_t)node * 32 + c * 8) = o;
    }
}

// ---- encoder GEMM: 64-row blocks. Whole A-tile (16KB) staged ONCE in fragment
// order (1 barrier), then a barrier-free K-loop. LDS = 32KB -> 5 blocks/CU.
__global__ __launch_bounds__(256) void k_enc(const unsigned short* __restrict__ A,
                                             const unsigned short* __restrict__ Whi,
                                             const unsigned short* __restrict__ Wlo,
                                             const float* __restrict__ bias,
                                             unsigned short* __restrict__ C) {
    constexpr int KS = 4;   // K = 128
    __shared__ __align__(16) unsigned short tls[16384];   // A-tile (first 8192) / z staging
    const int tid = threadIdx.x;
    const int m0 = blockIdx.x * 64;
    const int wid = tid >> 6, lane = tid & 63;
    const int lm = lane & 15, q = lane >> 4;
    const unsigned short* fh = Whi + (size_t)wid * 4 * KS * 512 + lane * 8;
    const unsigned short* fl = Wlo + (size_t)wid * 4 * KS * 512 + lane * 8;

    f32x4 acc[4][4];
#pragma unroll
    for (int i = 0; i < 4; ++i)
#pragma unroll
        for (int j = 0; j < 4; ++j) acc[i][j] = (f32x4){0.f, 0.f, 0.f, 0.f};

    // stage whole A-tile: 1024 x 16B chunks, 4 per thread, fragment order
#pragma unroll
    for (int c0 = 0; c0 < 4; ++c0) {
        int cid = c0 * 256 + tid;                 // = ks*256 + i*64 + l
        int ks = cid >> 8, rem = cid & 255;
        int row = (rem >> 6) * 16 + (rem & 15);
        int dq = (rem >> 4) & 3;
        gl_lds16(A + (size_t)ks * SLS + (size_t)(m0 + row) * 32 + dq * 8, &tls[cid * 8]);
    }
    __syncthreads();

#pragma unroll 2
    for (int ks = 0; ks < KS; ++ks) {
        bf16x8 af[4], bh[4], bl[4];
#pragma unroll
        for (int j = 0; j < 4; ++j) {
            bh[j] = *reinterpret_cast<const bf16x8*>(fh + (j * KS + ks) * 512);
            bl[j] = *reinterpret_cast<const bf16x8*>(fl + (j * KS + ks) * 512);
        }
#pragma unroll
        for (int i = 0; i < 4; ++i)
            af[i] = *reinterpret_cast<const bf16x8*>(&tls[(ks * 256 + i * 64 + lane) * 8]);
#pragma unroll
        for (int i = 0; i < 4; ++i)
#pragma unroll
            for (int j = 0; j < 4; ++j) {
                acc[i][j] = __builtin_amdgcn_mfma_f32_16x16x32_bf16(af[i], bl[j], acc[i][j], 0, 0, 0);
                acc[i][j] = __builtin_amdgcn_mfma_f32_16x16x32_bf16(af[i], bh[j], acc[i][j], 0, 0, 0);
            }
    }
    __syncthreads();   // all A reads done before z overwrites tls
    // stage C into LDS slice-major-local [sl][row][ch]
#pragma unroll
    for (int j = 0; j < 4; ++j) {
        int col = wid * 64 + j * 16 + lm;
        float bv = bias[col];
#pragma unroll
        for (int i = 0; i < 4; ++i) {
#pragma unroll
            for (int r = 0; r < 4; ++r)
                tls[(col >> 5) * 2048 + (i * 16 + q * 4 + r) * 32 + (col & 31)] =
                    f2bf(acc[i][j][r] + bv);
        }
    }
    __syncthreads();
#pragma unroll
    for (int c0 = 0; c0 < 8; ++c0) {
        int o = (c0 * 256 + tid) * 8;
        int sl = o >> 11;
        uint4 v = *reinterpret_cast<const uint4*>(&tls[o]);
        *reinterpret_cast<uint4*>(C + (size_t)sl * SLS + (size_t)m0 * 32 + (o - (sl << 11))) = v;
    }
}

// ---- fused MLP: z0 @ W1 + b1 -> relu -> t (LDS, fragment order) -> t @ W2 + b2
// -> z (LDS -> vectorized stores) + BN stats via REPLICATED global float atomics
// (replica = blockIdx & 7 -> ~98 atomics/address; unreplicated cost +14us/dispatch).
// 512 threads / 8 waves, barrier-free K-loops, j-pair wave split.
__global__ __launch_bounds__(512) void k_mlp(const unsigned short* __restrict__ Az,
                                             const unsigned short* __restrict__ W1h,
                                             const unsigned short* __restrict__ W1l,
                                             const float* __restrict__ b1,
                                             const unsigned short* __restrict__ W2h,
                                             const unsigned short* __restrict__ W2l,
                                             const float* __restrict__ b2,
                                             unsigned short* __restrict__ Z,
                                             float* __restrict__ sAB, int M) {
    constexpr int KS = 8;    // K = 256
    __shared__ __align__(16) unsigned short tls[16384];   // A-tile / t / z staging, 32KB
    const int tid = threadIdx.x;
    const int m0 = blockIdx.x * 64;
    const int wave = tid >> 6, lane = tid & 63;
    const int wid = wave >> 1;     // 64-col group 0..3
    const int jp  = wave & 1;      // j-pair 0..1 (j = jp*2 + j2)
    const int lm = lane & 15, q = lane >> 4;
    float* sABr = sAB + (blockIdx.x & (NREP - 1)) * 512;
    const unsigned short* f1h = W1h + (size_t)wid * 4 * KS * 512 + lane * 8;
    const unsigned short* f1l = W1l + (size_t)wid * 4 * KS * 512 + lane * 8;
    const unsigned short* f2h = W2h + (size_t)wid * 4 * KS * 512 + lane * 8;
    const unsigned short* f2l = W2l + (size_t)wid * 4 * KS * 512 + lane * 8;

    f32x4 acc[4][2];
#pragma unroll
    for (int i = 0; i < 4; ++i)
#pragma unroll
        for (int j = 0; j < 2; ++j) acc[i][j] = (f32x4){0.f, 0.f, 0.f, 0.f};

    // stage whole A-tile: 2048 x 16B chunks, 4 per thread, fragment order
#pragma unroll
    for (int c0 = 0; c0 < 4; ++c0) {
        int cid = c0 * 512 + tid;                 // = ks*256 + i*64 + l
        int ks = cid >> 8, rem = cid & 255;
        int row = (rem >> 6) * 16 + (rem & 15);
        int dq = (rem >> 4) & 3;
        gl_lds16(Az + (size_t)ks * SLS + (size_t)(m0 + row) * 32 + dq * 8, &tls[cid * 8]);
    }
    __syncthreads();

    // GEMM-1: barrier-free, B loads pipeline across iterations
#pragma unroll 2
    for (int ks = 0; ks < KS; ++ks) {
        bf16x8 af[4], bh[2], bl[2];
#pragma unroll
        for (int j2 = 0; j2 < 2; ++j2) {
            int j = jp * 2 + j2;
            bh[j2] = *reinterpret_cast<const bf16x8*>(f1h + (j * KS + ks) * 512);
            bl[j2] = *reinterpret_cast<const bf16x8*>(f1l + (j * KS + ks) * 512);
        }
#pragma unroll
        for (int i = 0; i < 4; ++i)
            af[i] = *reinterpret_cast<const bf16x8*>(&tls[(ks * 256 + i * 64 + lane) * 8]);
#pragma unroll
        for (int i = 0; i < 4; ++i)
#pragma unroll
            for (int j2 = 0; j2 < 2; ++j2) {
                acc[i][j2] = __builtin_amdgcn_mfma_f32_16x16x32_bf16(af[i], bl[j2], acc[i][j2], 0, 0, 0);
                acc[i][j2] = __builtin_amdgcn_mfma_f32_16x16x32_bf16(af[i], bh[j2], acc[i][j2], 0, 0, 0);
            }
    }
    __syncthreads();   // all A reads done before t overwrites tls
    // epilogue-1: t = relu(acc + b1) -> tls in FRAGMENT order
#pragma unroll
    for (int j2 = 0; j2 < 2; ++j2) {
        int col = wid * 64 + (jp * 2 + j2) * 16 + lm;
        float bv = b1[col];
        int ks2 = col >> 5;
        int q2 = (col >> 3) & 3;
        int e2 = col & 7;
#pragma unroll
        for (int i = 0; i < 4; ++i) {
#pragma unroll
            for (int r = 0; r < 4; ++r)
                tls[((i * 8 + ks2) * 64 + q2 * 16 + q * 4 + r) * 8 + e2] =
                    f2bf(fmaxf(acc[i][j2][r] + bv, 0.f));
        }
    }
    __syncthreads();

    // GEMM-2: A-fragments straight from tls (conflict-free), fragment B
#pragma unroll
    for (int i = 0; i < 4; ++i)
#pragma unroll
        for (int j = 0; j < 2; ++j) acc[i][j] = (f32x4){0.f, 0.f, 0.f, 0.f};
#pragma unroll 2
    for (int ks = 0; ks < KS; ++ks) {
        bf16x8 af[4], bh[2], bl[2];
#pragma unroll
        for (int j2 = 0; j2 < 2; ++j2) {
            int j = jp * 2 + j2;
            bh[j2] = *reinterpret_cast<const bf16x8*>(f2h + (j * KS + ks) * 512);
            bl[j2] = *reinterpret_cast<const bf16x8*>(f2l + (j * KS + ks) * 512);
        }
#pragma unroll
        for (int i = 0; i < 4; ++i)
            af[i] = *reinterpret_cast<const bf16x8*>(&tls[((i * 8 + ks) * 64 + lane) * 8]);
#pragma unroll
        for (int i = 0; i < 4; ++i)
#pragma unroll
            for (int j2 = 0; j2 < 2; ++j2) {
                acc[i][j2] = __builtin_amdgcn_mfma_f32_16x16x32_bf16(af[i], bl[j2], acc[i][j2], 0, 0, 0);
                acc[i][j2] = __builtin_amdgcn_mfma_f32_16x16x32_bf16(af[i], bh[j2], acc[i][j2], 0, 0, 0);
            }
    }
    __syncthreads();   // all tls reads done before overwrite with z

    // epilogue-2: stats (shfl-reduced, one replicated atomicAdd pair per col) + z -> tls
#pragma unroll
    for (int j2 = 0; j2 < 2; ++j2) {
        int col = wid * 64 + (jp * 2 + j2) * 16 + lm;
        float bv = b2[col];
        float s = 0.f, s2 = 0.f;
#pragma unroll
        for (int i = 0; i < 4; ++i) {
#pragma unroll
            for (int r = 0; r < 4; ++r) {
                int row = i * 16 + q * 4 + r;
                float v = acc[i][j2][r] + bv;
                if (m0 + row < M) { s += v; s2 = fmaf(v, v, s2); }
                tls[(col >> 5) * 2048 + row * 32 + (col & 31)] = f2bf(v);
            }
        }
        s += __shfl_xor(s, 16); s += __shfl_xor(s, 32);
        s2 += __shfl_xor(s2, 16); s2 += __shfl_xor(s2, 32);
        if (q == 0) {
            atomicAdd(&sABr[col], s);
            atomicAdd(&sABr[256 + col], s2);
        }
    }
    __syncthreads();
#pragma unroll
    for (int c0 = 0; c0 < 4; ++c0) {
        int o = (c0 * 512 + tid) * 8;
        int sl = o >> 11;
        uint4 v = *reinterpret_cast<const uint4*>(&tls[o]);
        *reinterpret_cast<uint4*>(Z + (size_t)sl * SLS + (size_t)m0 * 32 + (o - (sl << 11))) = v;
    }
}

// ---- vectorized graph mean-pool of relu(A*z+B); writes h back IN PLACE.
// BN affine (A,B) from the NREP replicated atomic stats (summed in prologue,
// L2-broadcast). 8 groups of 32 lanes; group = slice; lane = (rsub, cc).
__global__ void k_pool(unsigned short* __restrict__ z, const float* __restrict__ sAB,
                       const float* __restrict__ gamma, const float* __restrict__ beta,
                       const int* __restrict__ gstart, float* __restrict__ partl) {
    __shared__ float Asm[256], Bsm[256];
    int g = blockIdx.x, sp = blockIdx.y, tid = threadIdx.x;
    {
        float s = 0.f, s2 = 0.f;
#pragma unroll
        for (int r = 0; r < NREP; ++r) {
            s += sAB[r * 512 + tid];
            s2 += sAB[r * 512 + 256 + tid];
        }
        float mean = s * (1.f / N_NODES);
        float var = s2 * (1.f / N_NODES) - mean * mean;
        float inv = rsqrtf(var + 1e-5f);
        float A = gamma[tid] * inv;
        Asm[tid] = A;
        Bsm[tid] = beta[tid] - mean * A;
    }
    __syncthreads();
    int grp = tid >> 5, l = tid & 31;
    int rsub = l >> 2, cc = l & 3;
    float A[8], B[8];
#pragma unroll
    for (int i = 0; i < 8; ++i) {
        A[i] = Asm[grp * 32 + cc * 8 + i];
        B[i] = Bsm[grp * 32 + cc * 8 + i];
    }
    int beg = gstart[g], c = gstart[g + 1] - beg;
    int chunk = (c + 3) >> 2;
    int r0 = beg + sp * chunk;
    int r1 = beg + c;
    int rlim = r0 + chunk;
    if (rlim < r1) r1 = rlim;
    unsigned short* zp = z + (size_t)grp * SLS + cc * 8;
    float acc[8] = {0.f, 0.f, 0.f, 0.f, 0.f, 0.f, 0.f, 0.f};
    for (int r = r0 + rsub; r < r1; r += 8) {
        uint4 v = *reinterpret_cast<const uint4*>(zp + (size_t)r * 32);
        const unsigned short* pv = (const unsigned short*)&v;
        uint4 o;
        unsigned short* pw = (unsigned short*)&o;
#pragma unroll
        for (int i = 0; i < 8; ++i) {
            float x = fmaxf(fmaf(A[i], bf2f(pv[i]), B[i]), 0.f);
            pw[i] = f2bf(x);
            acc[i] += x;
        }
        *reinterpret_cast<uint4*>(zp + (size_t)r * 32) = o;
    }
#pragma unroll
    for (int m = 4; m <= 16; m <<= 1)
#pragma unroll
        for (int i = 0; i < 8; ++i) acc[i] += __shfl_xor(acc[i], m, 64);
    if (rsub == 0) {
        float* pp = partl + (size_t)(g * 4 + sp) * 256 + grp * 32 + cc * 8;
#pragma unroll
        for (int i = 0; i < 8; ++i) pp[i] = acc[i];
    }
}

// ---- FC head: sums pool partials, divides by cnt, 2-layer MLP
__global__ __launch_bounds__(1024) void k_fc(const float* __restrict__ part,
                                             const int* __restrict__ gstart,
                                             const float* __restrict__ W1,
                                             const float* __restrict__ b1,
                                             const float* __restrict__ W2,
                                             const float* __restrict__ b2,
                                             float* __restrict__ out) {
    __shared__ float gs[DIM * NLAYERS];
    __shared__ float pt[8][128];
    __shared__ float red2[2];
    int g = blockIdx.x, t = threadIdx.x;
    float invc = 1.f / fmaxf((float)(gstart[g + 1] - gstart[g]), 1.f);
    for (int i = t; i < DIM * NLAYERS; i += 1024) {
        int l = i >> 8, c = i & 255;
        const float* pl = part + ((size_t)(l * NGRAPHS + g) * 4) * 256 + c;
        gs[i] = (pl[0] + pl[256] + pl[512] + pl[768]) * invc;
    }
    __syncthreads();
    int o = t & 127, kk = t >> 7;
    float acc = 0.f;
    const float* wp = W1 + (size_t)(kk * 96) * 128 + o;
#pragma unroll 4
    for (int k = 0; k < 96; ++k) acc = fmaf(gs[kk * 96 + k], wp[(size_t)k * 128], acc);
    pt[kk][o] = acc;
    __syncthreads();
    if (t < 128) {
        float v = b1[o];
#pragma unroll
        for (int p = 0; p < 8; ++p) v += pt[p][o];
        v = fmaxf(v, 0.f) * W2[o];
#pragma unroll
        for (int off = 32; off; off >>= 1) v += __shfl_down(v, off, 64);
        if ((t & 63) == 0) red2[t >> 6] = v;
    }
    __syncthreads();
    if (t == 0) out[g] = red2[0] + red2[1] + b2[0];
}

extern "C" void kernel_launch(void* const* d_in, const int* in_sizes, int n_in,
                              void* d_out, int out_size, void* d_ws, size_t ws_size,
                              hipStream_t stream) {
    const float* x = (const float*)d_in[0];
    const int* ei = (const int*)d_in[1];
    const int* batch = (const int*)d_in[2];
    const float* W_enc = (const float*)d_in[4];
    const float* b_enc = (const float*)d_in[5];
    const float* W1 = (const float*)d_in[6];
    const float* b1 = (const float*)d_in[7];
    const float* W2 = (const float*)d_in[8];
    const float* b2 = (const float*)d_in[9];
    const float* gamma = (const float*)d_in[10];
    const float* beta = (const float*)d_in[11];
    const float* Wfc1 = (const float*)d_in[12];
    const float* bfc1 = (const float*)d_in[13];
    const float* Wfc2 = (const float*)d_in[14];
    const float* bfc2 = (const float*)d_in[15];
    float* out = (float*)d_out;
    const int* srcp = ei;
    const int* dstp = ei + N_EDGES;

    // Workspace bump allocator (~92 MB)
    char* w = (char*)d_ws;
    auto alloc = [&](size_t b) -> char* {
        char* p = w;
        w += (b + 255) & ~(size_t)255;
        return p;
    };
    unsigned short* xb   = (unsigned short*)alloc((size_t)N_PAD * F_INPUT * 2);  // [4][N_PAD][32]
    unsigned short* hbuf = (unsigned short*)alloc(8 * SLS * 2);  // enc out / z / h (in-place)
    unsigned short* zA   = (unsigned short*)alloc(8 * SLS * 2);  // agg out
    unsigned short* wench = (unsigned short*)alloc(F_INPUT * DIM * 2);
    unsigned short* wencl = (unsigned short*)alloc(F_INPUT * DIM * 2);
    unsigned short* w1h = (unsigned short*)alloc((size_t)NLAYERS * DIM * DIM * 2);
    unsigned short* w1l = (unsigned short*)alloc((size_t)NLAYERS * DIM * DIM * 2);
    unsigned short* w2h = (unsigned short*)alloc((size_t)NLAYERS * DIM * DIM * 2);
    unsigned short* w2l = (unsigned short*)alloc((size_t)NLAYERS * DIM * DIM * 2);
    unsigned short* csr16 = (unsigned short*)alloc((size_t)N_EDGES * 2);
    int* row_ptr = (int*)alloc((size_t)(N_NODES + 1) * 4);
    unsigned* slab = (unsigned*)alloc((size_t)NBH * 25000 * 4);
    int* deg = (int*)alloc((size_t)N_NODES * 4);
    int* basep = (int*)alloc((size_t)NBH * N_NODES * 4);
    int* gstart = (int*)alloc((NGRAPHS + 1) * 4);
    int* bsum = (int*)alloc(256 * 4);
    int* boff = (int*)alloc(256 * 4);
    float* sAB = (float*)alloc((size_t)NLAYERS * NREP * 512 * 4);  // replicated BN accumulators
    float* part = (float*)alloc((size_t)NLAYERS * NGRAPHS * 4 * 256 * 4);

    // prep: weights hi/lo fragment-packed + x->bf16 slice-major + stats zeroing
    k_prep<<<6250, 256, 0, stream>>>(W_enc, W1, W2, x, wench, wencl, w1h, w1l, w2h, w2l,
                                     xb, sAB);

    // CSR build (u16 indices), atomic-free
    const int NB = (N_NODES + 255) / 256;  // 196
    k_count<<<NBH, 512, 0, stream>>>(dstp, slab);
    k_degred<<<NB, 256, 0, stream>>>(slab, batch, deg, gstart);
    k_scan1<<<NB, 256, 0, stream>>>(deg, row_ptr + 1, bsum);
    k_scan2<<<1, 256, 0, stream>>>(bsum, boff, NB);
    k_scan3<<<NB, 256, 0, stream>>>(row_ptr, boff);
    k_base<<<NB, 256, 0, stream>>>(slab, row_ptr, basep);
    k_fill2<<<NBH, 512, 0, stream>>>(srcp, dstp, basep, csr16);

    // encoder: h = x @ W_enc + b_enc -> hbuf (slice-major)
    k_enc<<<NMB, 256, 0, stream>>>(xb, wench, wencl, b_enc, hbuf);

    dim3 pgrid(NGRAPHS, 4);
    const int AGRID = 782 * 8;
    for (int l = 0; l < NLAYERS; ++l) {
        k_agg<<<AGRID, 256, 0, stream>>>(hbuf, row_ptr, csr16, zA);
        k_mlp<<<NMB, 512, 0, stream>>>(zA, w1h + l * 65536, w1l + l * 65536, b1 + l * DIM,
                                       w2h + l * 65536, w2l + l * 65536, b2 + l * DIM,
                                       hbuf, sAB + l * NREP * 512, N_NODES);
        k_pool<<<pgrid, 256, 0, stream>>>(hbuf, sAB + l * NREP * 512, gamma + l * DIM,
                                          beta + l * DIM, gstart,
                                          part + (size_t)l * NGRAPHS * 4 * 256);
    }
    k_fc<<<NGRAPHS, 1024, 0, stream>>>(part, gstart, Wfc1, bfc1, Wfc2, bfc2, out);
}